// Round 4
// baseline (295.215 us; speedup 1.0000x reference)
//
#include <hip/hip_runtime.h>
#include <hip/hip_bf16.h>
#include <stdint.h>

// Problem constants (from reference)
#define N_TOKENS   4096
#define IN_FEAT    1024
#define OUT_FEAT   2048
#define NUM_EXPERT 16

// GEMM tiling
#define BM 128
#define BN 128
#define BK 32
#define MAX_TILES 48          // sum_e ceil(cnt_e/128) <= 47
#define MAX_ROWS  6144        // padded sorted rows upper bound (<=6016)

typedef __bf16 bf16x8 __attribute__((ext_vector_type(8)));
typedef float  f32x4  __attribute__((ext_vector_type(4)));
typedef unsigned short us8 __attribute__((ext_vector_type(8)));  // 16B

__device__ __forceinline__ unsigned short f32_to_bf16_rne(float f) {
  union { float f; uint32_t u; } v; v.f = f;
  uint32_t u = v.u;
  u += 0x7fffu + ((u >> 16) & 1u);   // round-nearest-even
  return (unsigned short)(u >> 16);
}

// async global->LDS, 16B per lane. LDS base must be wave-uniform; lane i
// lands at base + i*16. Source address is PER-LANE -> we use it to stage
// tiles in a K-chunk-major LDS layout (conflict-free fragment reads).
__device__ __forceinline__ void async_copy16(const void* g, void* l) {
  __builtin_amdgcn_global_load_lds(
      (const __attribute__((address_space(1))) unsigned int*)g,
      (__attribute__((address_space(3))) unsigned int*)l, 16, 0, 0);
}

// ---------------------------------------------------------------------------
// Kernel 1: routing setup (single block). Histogram, padded prefix, scatter.
// ---------------------------------------------------------------------------
__global__ void k_setup(const int* __restrict__ gate,
                        int* __restrict__ pstart,     // [16] padded seg start
                        int* __restrict__ tile_e,     // [MAX_TILES]
                        int* __restrict__ tile_m,     // [MAX_TILES]
                        int* __restrict__ row_token)  // [MAX_ROWS], -1 = pad
{
  __shared__ int cnt[NUM_EXPERT];
  __shared__ int cur[NUM_EXPERT];
  __shared__ int ps[NUM_EXPERT];
  const int tid = threadIdx.x;
  if (tid < NUM_EXPERT) { cnt[tid] = 0; cur[tid] = 0; }
  __syncthreads();
  for (int b = tid; b < N_TOKENS; b += 256) atomicAdd(&cnt[gate[b]], 1);
  for (int r = tid; r < MAX_ROWS; r += 256) row_token[r] = -1;
  __syncthreads();
  if (tid == 0) {
    int p = 0, tot = 0;
    for (int e = 0; e < NUM_EXPERT; ++e) {
      ps[e] = p; pstart[e] = p;
      int nt = (cnt[e] + BM - 1) / BM;
      for (int t = 0; t < nt; ++t) { tile_e[tot] = e; tile_m[tot] = t; ++tot; }
      p += nt * BM;
    }
    for (int s = tot; s < MAX_TILES; ++s) { tile_e[s] = -1; tile_m[s] = 0; }
  }
  __syncthreads();
  for (int b = tid; b < N_TOKENS; b += 256) {
    int e = gate[b];
    int pos = atomicAdd(&cur[e], 1);
    row_token[ps[e] + pos] = b;
  }
}

// ---------------------------------------------------------------------------
// Kernel 2: gather x into sorted padded order + cast to bf16; pads -> zeros.
// 2 rows per block; 128 threads/row; 16B stores.
// ---------------------------------------------------------------------------
__global__ void k_gather_x(const float4* __restrict__ x,
                           const int* __restrict__ row_token,
                           us8* __restrict__ xs) {
  const int r = blockIdx.x * 2 + (threadIdx.x >> 7);
  const int c = threadIdx.x & 127;
  const int tok = row_token[r];
  us8 o;
  if (tok >= 0) {
    float4 a = x[tok * 256 + c * 2];
    float4 b = x[tok * 256 + c * 2 + 1];
    o[0] = f32_to_bf16_rne(a.x); o[1] = f32_to_bf16_rne(a.y);
    o[2] = f32_to_bf16_rne(a.z); o[3] = f32_to_bf16_rne(a.w);
    o[4] = f32_to_bf16_rne(b.x); o[5] = f32_to_bf16_rne(b.y);
    o[6] = f32_to_bf16_rne(b.z); o[7] = f32_to_bf16_rne(b.w);
  } else {
    o = (us8)0;
  }
  xs[r * 128 + c] = o;
}

// ---------------------------------------------------------------------------
// Kernel 3: grouped GEMM, all-async staging (m97 structure).
// out[token, n] = sum_k xs[row, k] * w_f32[e][n][k]
// 128x128 tile, 4 waves (2x2), each wave 4x4 of mfma_f32_16x16x32_bf16.
//   A: bf16 from xs, 2 async rounds -> As, K-chunk-major [q=0..3][row][8bf16]
//   B: RAW fp32 from w, 4 async rounds -> Bs, K-chunk-major [q'=0..7][row][4f32]
// Fragment ds_read_b128: bank = f(row) only -> 2-way aliasing = free (m136).
// fp32->bf16 conversion happens in registers between ds_read and MFMA.
// ---------------------------------------------------------------------------
__global__ void __launch_bounds__(256)
k_gemm(const unsigned short* __restrict__ xs,   // [MAX_ROWS][IN_FEAT] bf16
       const float* __restrict__ w,             // [E][OUT_FEAT][IN_FEAT] fp32
       const int* __restrict__ pstart,
       const int* __restrict__ tile_e,
       const int* __restrict__ tile_m,
       const int* __restrict__ row_token,
       float* __restrict__ out) {
  __shared__ __attribute__((aligned(16))) unsigned short As[4096]; // 8 KB
  __shared__ __attribute__((aligned(16))) float Bs[4096];          // 16 KB
  __shared__ int rowtok_s[BM];

  const int slot = blockIdx.y;
  const int e = tile_e[slot];
  if (e < 0) return;
  const int seg0 = pstart[e] + tile_m[slot] * BM;
  const int n0 = blockIdx.x * BN;

  const int tid  = threadIdx.x;
  const int wid  = tid >> 6;
  const int lane = tid & 63;
  const int lr   = lane & 15;
  const int quad = lane >> 4;
  const int wm   = (wid >> 1) * 64;   // wave m-offset in tile
  const int wn   = (wid & 1) * 64;    // wave n-offset in tile

  if (tid < BM) rowtok_s[tid] = row_token[seg0 + tid];

  // Staging: slot s = round*256 + tid; plane q = s>>7, row = s&127.
  // => row = tid&127, plane parity shi = tid>>7; round advances plane by 2.
  const int srow = tid & 127;
  const int shi  = tid >> 7;
  const unsigned short* agp = xs + (size_t)(seg0 + srow) * IN_FEAT + shi * 8;
  const float* bgp = w + (size_t)e * OUT_FEAT * IN_FEAT
                       + (size_t)(n0 + srow) * IN_FEAT + shi * 4;

  // wave-uniform LDS staging bases (lane i -> +i*16B)
  unsigned short* asd = &As[wid * 512];   // round rA adds 2048 shorts (4KB)
  float*          bsd = &Bs[wid * 256];   // round rB adds 1024 floats (4KB)

  // fragment read bases (K-chunk-major planes)
  const unsigned short* pA = &As[(quad * 128 + wm + lr) * 8];
  const float*          pB = &Bs[quad * 1024 + (wn + lr) * 4]; // plane 2*quad

  f32x4 acc[4][4];
  const f32x4 z = {0.f, 0.f, 0.f, 0.f};
#pragma unroll
  for (int i = 0; i < 4; ++i)
#pragma unroll
    for (int j = 0; j < 4; ++j) acc[i][j] = z;

  for (int k0 = 0; k0 < IN_FEAT; k0 += BK) {
    // 6 back-to-back async issues, one drain at the barrier (m97 pattern).
    async_copy16(agp + k0,      asd);          // A plane 0|1 (shi)
    async_copy16(agp + k0 + 16, asd + 2048);   // A plane 2|3
    async_copy16(bgp + k0,      bsd);          // B plane 0|1
    async_copy16(bgp + k0 + 8,  bsd + 1024);   // B plane 2|3
    async_copy16(bgp + k0 + 16, bsd + 2048);   // B plane 4|5
    async_copy16(bgp + k0 + 24, bsd + 3072);   // B plane 6|7
    __syncthreads();

    bf16x8 af[4], bf[4];
#pragma unroll
    for (int mi = 0; mi < 4; ++mi)
      af[mi] = *(const bf16x8*)(pA + mi * 128);       // +mi*16 rows
#pragma unroll
    for (int ni = 0; ni < 4; ++ni) {
      f32x4 c0 = *(const f32x4*)(pB + ni * 64);        // plane 2*quad
      f32x4 c1 = *(const f32x4*)(pB + 512 + ni * 64);  // plane 2*quad+1
      bf16x8 b;
      b[0] = (__bf16)c0[0]; b[1] = (__bf16)c0[1];
      b[2] = (__bf16)c0[2]; b[3] = (__bf16)c0[3];
      b[4] = (__bf16)c1[0]; b[5] = (__bf16)c1[1];
      b[6] = (__bf16)c1[2]; b[7] = (__bf16)c1[3];
      bf[ni] = b;
    }
#pragma unroll
    for (int mi = 0; mi < 4; ++mi)
#pragma unroll
      for (int ni = 0; ni < 4; ++ni)
        acc[mi][ni] = __builtin_amdgcn_mfma_f32_16x16x32_bf16(
            af[mi], bf[ni], acc[mi][ni], 0, 0, 0);
    __syncthreads();   // protect LDS before next stage overwrite
  }

  // Epilogue: C/D layout col=lane&15, row=quad*4+reg (verified m89/m91).
#pragma unroll
  for (int mi = 0; mi < 4; ++mi) {
    const int mb = wm + mi * 16 + quad * 4;
    const int t0 = rowtok_s[mb + 0];
    const int t1 = rowtok_s[mb + 1];
    const int t2 = rowtok_s[mb + 2];
    const int t3 = rowtok_s[mb + 3];
#pragma unroll
    for (int ni = 0; ni < 4; ++ni) {
      const int n = n0 + wn + ni * 16 + lr;
      f32x4 c = acc[mi][ni];
      if (t0 >= 0) out[(size_t)t0 * OUT_FEAT + n] = c[0];
      if (t1 >= 0) out[(size_t)t1 * OUT_FEAT + n] = c[1];
      if (t2 >= 0) out[(size_t)t2 * OUT_FEAT + n] = c[2];
      if (t3 >= 0) out[(size_t)t3 * OUT_FEAT + n] = c[3];
    }
  }
}

// ---------------------------------------------------------------------------
extern "C" void kernel_launch(void* const* d_in, const int* in_sizes, int n_in,
                              void* d_out, int out_size, void* d_ws, size_t ws_size,
                              hipStream_t stream) {
  const float* x    = (const float*)d_in[0];
  const int*   gate = (const int*)d_in[1];
  const float* w    = (const float*)d_in[2];
  float* out = (float*)d_out;

  // workspace layout (~13 MB)
  char* ws = (char*)d_ws;
  unsigned short* xs = (unsigned short*)ws;                        // 12 MB
  int* row_token = (int*)(ws + 12582912);                          // 24 KB
  int* pstart = row_token + MAX_ROWS;
  int* tile_e = pstart + NUM_EXPERT;
  int* tile_m = tile_e + MAX_TILES;

  k_setup<<<1, 256, 0, stream>>>(gate, pstart, tile_e, tile_m, row_token);
  k_gather_x<<<MAX_ROWS / 2, 256, 0, stream>>>((const float4*)x, row_token,
                                               (us8*)xs);
  dim3 g(OUT_FEAT / BN, MAX_TILES);
  k_gemm<<<g, 256, 0, stream>>>(xs, w, pstart, tile_e, tile_m, row_token, out);
}

// Round 5
// 261.515 us; speedup vs baseline: 1.1289x; 1.1289x over previous
//
#include <hip/hip_runtime.h>
#include <hip/hip_bf16.h>
#include <stdint.h>

// Problem constants (from reference)
#define N_TOKENS   4096
#define IN_FEAT    1024
#define OUT_FEAT   2048
#define NUM_EXPERT 16

// GEMM tiling
#define BM 128
#define BN 128
#define BK 32
#define MAX_TILES 48          // sum_e ceil(cnt_e/128) <= 47
#define MAX_ROWS  6144        // padded sorted rows upper bound (<=6016)

typedef __bf16 bf16x8 __attribute__((ext_vector_type(8)));
typedef float  f32x4  __attribute__((ext_vector_type(4)));
typedef unsigned short us8 __attribute__((ext_vector_type(8)));  // 16B

__device__ __forceinline__ unsigned short f32_to_bf16_rne(float f) {
  union { float f; uint32_t u; } v; v.f = f;
  uint32_t u = v.u;
  u += 0x7fffu + ((u >> 16) & 1u);   // round-nearest-even
  return (unsigned short)(u >> 16);
}

// async global->LDS, 16B per lane. LDS base wave-uniform; lane i lands at
// base + i*16. Source address is PER-LANE.
__device__ __forceinline__ void async_copy16(const void* g, void* l) {
  __builtin_amdgcn_global_load_lds(
      (const __attribute__((address_space(1))) unsigned int*)g,
      (__attribute__((address_space(3))) unsigned int*)l, 16, 0, 0);
}

// ---------------------------------------------------------------------------
// Kernel 1: routing setup (single block). Histogram, padded prefix, scatter.
// ---------------------------------------------------------------------------
__global__ void k_setup(const int* __restrict__ gate,
                        int* __restrict__ pstart,     // [16] padded seg start
                        int* __restrict__ tile_e,     // [MAX_TILES]
                        int* __restrict__ tile_m,     // [MAX_TILES]
                        int* __restrict__ row_token)  // [MAX_ROWS], -1 = pad
{
  __shared__ int cnt[NUM_EXPERT];
  __shared__ int cur[NUM_EXPERT];
  __shared__ int ps[NUM_EXPERT];
  const int tid = threadIdx.x;
  if (tid < NUM_EXPERT) { cnt[tid] = 0; cur[tid] = 0; }
  __syncthreads();
  for (int b = tid; b < N_TOKENS; b += 256) atomicAdd(&cnt[gate[b]], 1);
  for (int r = tid; r < MAX_ROWS; r += 256) row_token[r] = -1;
  __syncthreads();
  if (tid == 0) {
    int p = 0, tot = 0;
    for (int e = 0; e < NUM_EXPERT; ++e) {
      ps[e] = p; pstart[e] = p;
      int nt = (cnt[e] + BM - 1) / BM;
      for (int t = 0; t < nt; ++t) { tile_e[tot] = e; tile_m[tot] = t; ++tot; }
      p += nt * BM;
    }
    for (int s = tot; s < MAX_TILES; ++s) { tile_e[s] = -1; tile_m[s] = 0; }
  }
  __syncthreads();
  for (int b = tid; b < N_TOKENS; b += 256) {
    int e = gate[b];
    int pos = atomicAdd(&cur[e], 1);
    row_token[ps[e] + pos] = b;
  }
}

// ---------------------------------------------------------------------------
// Kernel 2: gather x into sorted padded order + cast to bf16; pads -> zeros.
// ---------------------------------------------------------------------------
__global__ void k_gather_x(const float4* __restrict__ x,
                           const int* __restrict__ row_token,
                           us8* __restrict__ xs) {
  const int r = blockIdx.x * 2 + (threadIdx.x >> 7);
  const int c = threadIdx.x & 127;
  const int tok = row_token[r];
  us8 o;
  if (tok >= 0) {
    float4 a = x[tok * 256 + c * 2];
    float4 b = x[tok * 256 + c * 2 + 1];
    o[0] = f32_to_bf16_rne(a.x); o[1] = f32_to_bf16_rne(a.y);
    o[2] = f32_to_bf16_rne(a.z); o[3] = f32_to_bf16_rne(a.w);
    o[4] = f32_to_bf16_rne(b.x); o[5] = f32_to_bf16_rne(b.y);
    o[6] = f32_to_bf16_rne(b.z); o[7] = f32_to_bf16_rne(b.w);
  } else {
    o = (us8)0;
  }
  xs[r * 128 + c] = o;
}

// ---------------------------------------------------------------------------
// Kernel 3: grouped GEMM, all-async staging, XOR-swizzled LDS.
// out[token, n] = sum_k xs[row, k] * w_f32[e][n][k]
// 128x128 tile, 4 waves (2x2), each wave 4x4 of mfma_f32_16x16x32_bf16.
//   A (bf16): slot(r,c) = r*4 + (c ^ ((r>>1)&3)), c = 16B chunk 0..3.
//     staging: 4 lanes = one full 64B row-window (coalesced, 16 txn/instr);
//     frag read bank-group = 4*(lr&1) + (quad^((lr>>1)&3)) -> 2-way = free.
//   B (fp32): slot(r,c) = r*8 + (c ^ (r&7)), c = 16B chunk 0..7.
//     staging: 8 lanes = one full 128B row; wave-instr = 8 contiguous rows
//     = 1KB (16 txn); frag read group = (2q+j)^(lr&7) -> 2-way = free.
// fp32->bf16 convert in registers between ds_read and MFMA.
// ---------------------------------------------------------------------------
__global__ void __launch_bounds__(256)
k_gemm(const unsigned short* __restrict__ xs,   // [MAX_ROWS][IN_FEAT] bf16
       const float* __restrict__ w,             // [E][OUT_FEAT][IN_FEAT] fp32
       const int* __restrict__ pstart,
       const int* __restrict__ tile_e,
       const int* __restrict__ tile_m,
       const int* __restrict__ row_token,
       float* __restrict__ out) {
  __shared__ us8   As[512];    // 8 KB
  __shared__ f32x4 Bs[1024];   // 16 KB
  __shared__ int rowtok_s[BM];

  const int slot = blockIdx.y;
  const int e = tile_e[slot];
  if (e < 0) return;
  const int seg0 = pstart[e] + tile_m[slot] * BM;
  const int n0 = blockIdx.x * BN;

  const int tid  = threadIdx.x;
  const int wid  = tid >> 6;
  const int lane = tid & 63;
  const int lr   = lane & 15;
  const int quad = lane >> 4;
  const int wm   = (wid >> 1) * 64;   // wave m-offset in tile
  const int wn   = (wid & 1) * 64;    // wave n-offset in tile

  if (tid < BM) rowtok_s[tid] = row_token[seg0 + tid];

  // Staging sources. Slot s = t*256 + tid; swizzled chunk is round-invariant:
  const int cA = (tid & 3) ^ ((tid >> 3) & 3);   // A chunk (16B) within row
  const int cB = (tid & 7) ^ ((tid >> 3) & 7);   // B chunk (16B) within row
  const unsigned short* agp = xs + (size_t)(seg0 + (tid >> 2)) * IN_FEAT + cA * 8;
  const float* bgp = w + (size_t)e * OUT_FEAT * IN_FEAT
                       + (size_t)(n0 + (tid >> 3)) * IN_FEAT + cB * 4;

  f32x4 acc[4][4];
  const f32x4 z = {0.f, 0.f, 0.f, 0.f};
#pragma unroll
  for (int i = 0; i < 4; ++i)
#pragma unroll
    for (int j = 0; j < 4; ++j) acc[i][j] = z;

  for (int k0 = 0; k0 < IN_FEAT; k0 += BK) {
    // 6 back-to-back async issues, one drain at the barrier.
    async_copy16(agp + k0,                 As + wid * 64);         // A t=0
    async_copy16(agp + 64 * IN_FEAT + k0,  As + 256 + wid * 64);   // A t=1
    async_copy16(bgp + k0,                 Bs + wid * 64);         // B t=0
    async_copy16(bgp + 32 * IN_FEAT + k0,  Bs + 256 + wid * 64);   // B t=1
    async_copy16(bgp + 64 * IN_FEAT + k0,  Bs + 512 + wid * 64);   // B t=2
    async_copy16(bgp + 96 * IN_FEAT + k0,  Bs + 768 + wid * 64);   // B t=3
    __syncthreads();

    bf16x8 af[4], bf[4];
#pragma unroll
    for (int mi = 0; mi < 4; ++mi) {
      const int n = wm + mi * 16 + lr;
      af[mi] = *(const bf16x8*)&As[n * 4 + (quad ^ ((n >> 1) & 3))];
    }
#pragma unroll
    for (int ni = 0; ni < 4; ++ni) {
      const int n = wn + ni * 16 + lr;
      f32x4 c0 = Bs[n * 8 + ((2 * quad)     ^ (n & 7))];
      f32x4 c1 = Bs[n * 8 + ((2 * quad + 1) ^ (n & 7))];
      bf16x8 b;
      b[0] = (__bf16)c0[0]; b[1] = (__bf16)c0[1];
      b[2] = (__bf16)c0[2]; b[3] = (__bf16)c0[3];
      b[4] = (__bf16)c1[0]; b[5] = (__bf16)c1[1];
      b[6] = (__bf16)c1[2]; b[7] = (__bf16)c1[3];
      bf[ni] = b;
    }
#pragma unroll
    for (int mi = 0; mi < 4; ++mi)
#pragma unroll
      for (int ni = 0; ni < 4; ++ni)
        acc[mi][ni] = __builtin_amdgcn_mfma_f32_16x16x32_bf16(
            af[mi], bf[ni], acc[mi][ni], 0, 0, 0);
    __syncthreads();   // protect LDS before next stage overwrite
  }

  // Epilogue: C/D layout col=lane&15, row=quad*4+reg (verified m89/m91).
#pragma unroll
  for (int mi = 0; mi < 4; ++mi) {
    const int mb = wm + mi * 16 + quad * 4;
    const int t0 = rowtok_s[mb + 0];
    const int t1 = rowtok_s[mb + 1];
    const int t2 = rowtok_s[mb + 2];
    const int t3 = rowtok_s[mb + 3];
#pragma unroll
    for (int ni = 0; ni < 4; ++ni) {
      const int n = n0 + wn + ni * 16 + lr;
      f32x4 c = acc[mi][ni];
      if (t0 >= 0) out[(size_t)t0 * OUT_FEAT + n] = c[0];
      if (t1 >= 0) out[(size_t)t1 * OUT_FEAT + n] = c[1];
      if (t2 >= 0) out[(size_t)t2 * OUT_FEAT + n] = c[2];
      if (t3 >= 0) out[(size_t)t3 * OUT_FEAT + n] = c[3];
    }
  }
}

// ---------------------------------------------------------------------------
extern "C" void kernel_launch(void* const* d_in, const int* in_sizes, int n_in,
                              void* d_out, int out_size, void* d_ws, size_t ws_size,
                              hipStream_t stream) {
  const float* x    = (const float*)d_in[0];
  const int*   gate = (const int*)d_in[1];
  const float* w    = (const float*)d_in[2];
  float* out = (float*)d_out;

  // workspace layout (~13 MB)
  char* ws = (char*)d_ws;
  unsigned short* xs = (unsigned short*)ws;                        // 12 MB
  int* row_token = (int*)(ws + 12582912);                          // 24 KB
  int* pstart = row_token + MAX_ROWS;
  int* tile_e = pstart + NUM_EXPERT;
  int* tile_m = tile_e + MAX_TILES;

  k_setup<<<1, 256, 0, stream>>>(gate, pstart, tile_e, tile_m, row_token);
  k_gather_x<<<MAX_ROWS / 2, 256, 0, stream>>>((const float4*)x, row_token,
                                               (us8*)xs);
  dim3 g(OUT_FEAT / BN, MAX_TILES);
  k_gemm<<<g, 256, 0, stream>>>(xs, w, pstart, tile_e, tile_m, row_token, out);
}